// Round 2
// baseline (411.567 us; speedup 1.0000x reference)
//
#include <hip/hip_runtime.h>
#include <math.h>

// Problem constants
#define NVEC   65536      // B*H*W = 64*32*32
#define CDIM   64
#define KBOOK  1024
#define NTOT   4194304    // B*C*H*W

// d_out layout (float32): [quantized_z: NTOT][quantized_z_st: NTOT][indices: NVEC][perplexity: 1]
// workspace: int finalIdx[NVEC] @0 ; float se[KBOOK] @262144 ; int hist[KBOOK] @266336(aligned 266240)

__global__ void zero_kernel(int* hist) {
    int t = blockIdx.x * 256 + threadIdx.x;
    if (t < KBOOK) hist[t] = 0;
}

// ||e_k||^2 replicating np.sum(cb**2, axis=1): fp32 squares + numpy pairwise
// 8-accumulator sum (n=64), all with non-contractable rn intrinsics.
__global__ void se_kernel(const float* __restrict__ cb, float* __restrict__ se) {
    int k = blockIdx.x * 256 + threadIdx.x;
    if (k >= KBOOK) return;
    const float* row = cb + k * CDIM;
    float r[8];
#pragma unroll
    for (int j = 0; j < 8; ++j) r[j] = __fmul_rn(row[j], row[j]);
#pragma unroll
    for (int i = 8; i < 64; i += 8)
#pragma unroll
        for (int j = 0; j < 8; ++j) r[j] = __fadd_rn(r[j], __fmul_rn(row[i + j], row[i + j]));
    float s = __fadd_rn(__fadd_rn(__fadd_rn(r[0], r[1]), __fadd_rn(r[2], r[3])),
                        __fadd_rn(__fadd_rn(r[4], r[5]), __fadd_rn(r[6], r[7])));
    se[k] = s;
}

// Bit-exact replication of:
//   dists = fl( fl(sx_n + se_k) - P_nk ),  P = (2*flat_z) @ cb.T with
//   ascending-k fma chain from 0 (BLAS microkernel semantics), argmin first-min.
__launch_bounds__(128)
__global__ void argmin_kernel(const float* __restrict__ z, const float* __restrict__ cb,
                              const float* __restrict__ se, int* __restrict__ outIdx) {
    __shared__ float tile[64 * CDIM];
    __shared__ float set_[64];
    const int t = threadIdx.x;
    const int n = blockIdx.x * 128 + t;
    const int b = n >> 10, hw = n & 1023;
    const float* zb = z + (size_t)b * (CDIM * 1024) + hw;

    // zx = 2*z (exact); sx = numpy pairwise 8-acc sum of fl(z^2)
    float zx[CDIM];
    float r[8];
#pragma unroll
    for (int c = 0; c < CDIM; ++c) {
        float zc = zb[c * 1024];
        zx[c] = zc + zc;
        float q = __fmul_rn(zc, zc);
        if (c < 8) r[c] = q;
        else r[c & 7] = __fadd_rn(r[c & 7], q);
    }
    const float sx = __fadd_rn(__fadd_rn(__fadd_rn(r[0], r[1]), __fadd_rn(r[2], r[3])),
                               __fadd_rn(__fadd_rn(r[4], r[5]), __fadd_rn(r[6], r[7])));

    float best = 3.4e38f;
    int bi = 0;

    for (int kt = 0; kt < KBOOK / 64; ++kt) {
        __syncthreads();
        const float4* src = (const float4*)(cb + kt * 64 * CDIM);
        float4* dst = (float4*)tile;
        for (int i = t; i < 1024; i += 128) dst[i] = src[i];
        if (t < 64) set_[t] = se[kt * 64 + t];
        __syncthreads();

        for (int e = 0; e < 64; e += 2) {
            const float* r0 = tile + e * CDIM;
            const float* r1 = r0 + CDIM;
            float a0 = 0.0f, a1 = 0.0f;   // ascending-c fma chains (k = column of A)
#pragma unroll
            for (int c = 0; c < CDIM; ++c) {
                a0 = fmaf(zx[c], r0[c], a0);
                a1 = fmaf(zx[c], r1[c], a1);
            }
            const float d0 = __fsub_rn(__fadd_rn(sx, set_[e]), a0);
            const float d1 = __fsub_rn(__fadd_rn(sx, set_[e + 1]), a1);
            const int k0 = kt * 64 + e;
            if (d0 < best) { best = d0; bi = k0; }       // strict <: first-min ties
            if (d1 < best) { best = d1; bi = k0 + 1; }
        }
    }
    outIdx[n] = bi;
}

// quantized_z = cb[idx] (exact copy); quantized_z_st = fl(z + fl(q - z))
__global__ void scatter_kernel(const float* __restrict__ z, const float* __restrict__ cb,
                               const int* __restrict__ idx, float* __restrict__ out) {
    const int o = blockIdx.x * 256 + threadIdx.x;          // o in [0, NTOT)
    const int b = o >> 16, c = (o >> 10) & 63, hw = o & 1023;
    const int n = (b << 10) | hw;
    const int k = idx[n];
    const float q = cb[k * CDIM + c];
    const float zv = z[o];
    out[o] = q;
    out[NTOT + o] = __fadd_rn(zv, __fsub_rn(q, zv));
}

// histogram + indices-as-float
__global__ void hist_kernel(const int* __restrict__ idx, int* __restrict__ hist,
                            float* __restrict__ outIdxF) {
    __shared__ int lh[KBOOK];
    for (int i = threadIdx.x; i < KBOOK; i += 256) lh[i] = 0;
    __syncthreads();
    const int n = blockIdx.x * 256 + threadIdx.x;          // grid = 256 blocks
    const int k = idx[n];
    outIdxF[n] = (float)k;
    atomicAdd(&lh[k], 1);
    __syncthreads();
    for (int i = threadIdx.x; i < KBOOK; i += 256)
        if (lh[i]) atomicAdd(&hist[i], lh[i]);
}

__global__ void perp_kernel(const int* __restrict__ hist, float* __restrict__ out) {
    __shared__ double partial[16];
    const int t = threadIdx.x;  // 1024 threads
    const int c = hist[t];
    double term = 0.0;
    if (c > 0) { double p = (double)c / (double)NVEC; term = p * log(p); }
    for (int off = 32; off > 0; off >>= 1) term += __shfl_down(term, off);
    if ((t & 63) == 0) partial[t >> 6] = term;
    __syncthreads();
    if (t == 0) {
        double s = 0.0;
        for (int i = 0; i < 16; ++i) s += partial[i];
        out[2 * NTOT + NVEC] = (float)exp(-s);
    }
}

extern "C" void kernel_launch(void* const* d_in, const int* in_sizes, int n_in,
                              void* d_out, int out_size, void* d_ws, size_t ws_size,
                              hipStream_t stream) {
    const float* z  = (const float*)d_in[0];   // [64,64,32,32]
    const float* cb = (const float*)d_in[1];   // [1024,64]
    float* out = (float*)d_out;

    char* ws = (char*)d_ws;
    int*   finalIdx = (int*)(ws + 0);
    float* se       = (float*)(ws + 262144);
    int*   hist     = (int*)(ws + 266240);

    zero_kernel<<<4, 256, 0, stream>>>(hist);
    se_kernel<<<4, 256, 0, stream>>>(cb, se);
    argmin_kernel<<<NVEC / 128, 128, 0, stream>>>(z, cb, se, finalIdx);
    scatter_kernel<<<NTOT / 256, 256, 0, stream>>>(z, cb, finalIdx, out);
    hist_kernel<<<NVEC / 256, 256, 0, stream>>>(finalIdx, hist, out + 2 * NTOT);
    perp_kernel<<<1, 1024, 0, stream>>>(hist, out);
}

// Round 3
// 341.675 us; speedup vs baseline: 1.2046x; 1.2046x over previous
//
#include <hip/hip_runtime.h>
#include <math.h>

// Problem constants
#define NVEC   65536      // B*H*W = 64*32*32
#define CDIM   64
#define KBOOK  1024
#define NTOT   4194304    // B*C*H*W

// d_out layout (float32): [quantized_z: NTOT][quantized_z_st: NTOT][indices: NVEC][perplexity: 1]
// workspace: u64 keys[NVEC] @0 ; float se[KBOOK] @524288 ; int hist[KBOOK] @528384

__global__ void init_kernel(unsigned long long* keys, int* hist) {
    int t = blockIdx.x * 256 + threadIdx.x;   // grid 256 -> t in [0, NVEC)
    keys[t] = 0xFFFFFFFFFFFFFFFFull;
    if (t < KBOOK) hist[t] = 0;
}

// ||e_k||^2 replicating np.sum(cb**2, axis=1): fp32 squares + numpy pairwise
// 8-accumulator sum (n=64), non-contractable rn intrinsics. (bit-exact, keep)
__global__ void se_kernel(const float* __restrict__ cb, float* __restrict__ se) {
    int k = blockIdx.x * 256 + threadIdx.x;
    if (k >= KBOOK) return;
    const float* row = cb + k * CDIM;
    float r[8];
#pragma unroll
    for (int j = 0; j < 8; ++j) r[j] = __fmul_rn(row[j], row[j]);
#pragma unroll
    for (int i = 8; i < 64; i += 8)
#pragma unroll
        for (int j = 0; j < 8; ++j) r[j] = __fadd_rn(r[j], __fmul_rn(row[i + j], row[i + j]));
    se[k] = __fadd_rn(__fadd_rn(__fadd_rn(r[0], r[1]), __fadd_rn(r[2], r[3])),
                      __fadd_rn(__fadd_rn(r[4], r[5]), __fadd_rn(r[6], r[7])));
}

// Bit-exact dists = fl(fl(sx+se_k) - a_nk), a = ascending-c fmaf chain on zx=2z.
// Codebook read with wave-uniform addresses -> SMEM (scalar pipe), no LDS.
// K split in half over blockIdx.y; halves merged via ordered-key atomicMin
// (value-then-index lexicographic == numpy first-min argmin).
__launch_bounds__(128, 2)
__global__ void argmin_kernel(const float* __restrict__ z, const float* __restrict__ cb,
                              const float* __restrict__ se,
                              unsigned long long* __restrict__ keys) {
    const int t = threadIdx.x;
    const int n = blockIdx.x * 128 + t;
    const int k0 = blockIdx.y * (KBOOK / 2);
    const int b = n >> 10, hw = n & 1023;
    const float* zb = z + (size_t)b * (CDIM * 1024) + hw;

    // zx = 2*z (exact); sx = numpy pairwise 8-acc sum of fl(z^2)
    float zx[CDIM];
    float r[8];
#pragma unroll
    for (int c = 0; c < CDIM; ++c) {
        float zc = zb[c * 1024];
        zx[c] = zc + zc;
        float q = __fmul_rn(zc, zc);
        if (c < 8) r[c] = q;
        else r[c & 7] = __fadd_rn(r[c & 7], q);
    }
    const float sx = __fadd_rn(__fadd_rn(__fadd_rn(r[0], r[1]), __fadd_rn(r[2], r[3])),
                               __fadd_rn(__fadd_rn(r[4], r[5]), __fadd_rn(r[6], r[7])));

    float best = 3.4e38f;
    int bi = k0;

    for (int k = k0; k < k0 + KBOOK / 2; k += 4) {
        const float* __restrict__ row = cb + (size_t)k * CDIM;  // uniform address
        float a0 = 0.f, a1 = 0.f, a2 = 0.f, a3 = 0.f;           // 4 indep chains (ILP)
#pragma unroll
        for (int c = 0; c < CDIM; ++c) {
            a0 = fmaf(zx[c], row[c], a0);
            a1 = fmaf(zx[c], row[c + CDIM], a1);
            a2 = fmaf(zx[c], row[c + 2 * CDIM], a2);
            a3 = fmaf(zx[c], row[c + 3 * CDIM], a3);
        }
        const float d0 = __fsub_rn(__fadd_rn(sx, se[k]), a0);
        const float d1 = __fsub_rn(__fadd_rn(sx, se[k + 1]), a1);
        const float d2 = __fsub_rn(__fadd_rn(sx, se[k + 2]), a2);
        const float d3 = __fsub_rn(__fadd_rn(sx, se[k + 3]), a3);
        if (d0 < best) { best = d0; bi = k; }        // strict <, ascending k: first-min
        if (d1 < best) { best = d1; bi = k + 1; }
        if (d2 < best) { best = d2; bi = k + 2; }
        if (d3 < best) { best = d3; bi = k + 3; }
    }

    // ordered-float key: monotonic uint32 over all floats; idx in low bits
    unsigned int ob = __float_as_uint(best);
    ob = (ob & 0x80000000u) ? ~ob : (ob | 0x80000000u);
    atomicMin(&keys[n], ((unsigned long long)ob << 32) | (unsigned int)bi);
}

// quantized_z = cb[idx]; quantized_z_st = fl(z + fl(q - z)); float4-vectorized
__global__ void scatter_kernel(const float* __restrict__ z, const float* __restrict__ cb,
                               const unsigned long long* __restrict__ keys,
                               float* __restrict__ out) {
    const int o = (blockIdx.x * 256 + threadIdx.x) * 4;    // [0, NTOT), step 4
    const int b = o >> 16, c = (o >> 10) & 63, hw = o & 1023;
    const int n = (b << 10) | hw;
    float q[4];
#pragma unroll
    for (int j = 0; j < 4; ++j) {
        const int k = (int)(keys[n + j] & 0xFFFFFFFFu);
        q[j] = cb[k * CDIM + c];
    }
    const float4 zv = *(const float4*)(z + o);
    *(float4*)(out + o) = make_float4(q[0], q[1], q[2], q[3]);
    float4 st;
    st.x = __fadd_rn(zv.x, __fsub_rn(q[0], zv.x));
    st.y = __fadd_rn(zv.y, __fsub_rn(q[1], zv.y));
    st.z = __fadd_rn(zv.z, __fsub_rn(q[2], zv.z));
    st.w = __fadd_rn(zv.w, __fsub_rn(q[3], zv.w));
    *(float4*)(out + NTOT + o) = st;
}

// histogram + indices-as-float
__global__ void hist_kernel(const unsigned long long* __restrict__ keys, int* __restrict__ hist,
                            float* __restrict__ outIdxF) {
    __shared__ int lh[KBOOK];
    for (int i = threadIdx.x; i < KBOOK; i += 256) lh[i] = 0;
    __syncthreads();
    const int n = blockIdx.x * 256 + threadIdx.x;          // grid = 256 blocks
    const int k = (int)(keys[n] & 0xFFFFFFFFu);
    outIdxF[n] = (float)k;
    atomicAdd(&lh[k], 1);
    __syncthreads();
    for (int i = threadIdx.x; i < KBOOK; i += 256)
        if (lh[i]) atomicAdd(&hist[i], lh[i]);
}

__global__ void perp_kernel(const int* __restrict__ hist, float* __restrict__ out) {
    __shared__ double partial[16];
    const int t = threadIdx.x;  // 1024 threads
    const int c = hist[t];
    double term = 0.0;
    if (c > 0) { double p = (double)c / (double)NVEC; term = p * log(p); }
    for (int off = 32; off > 0; off >>= 1) term += __shfl_down(term, off);
    if ((t & 63) == 0) partial[t >> 6] = term;
    __syncthreads();
    if (t == 0) {
        double s = 0.0;
        for (int i = 0; i < 16; ++i) s += partial[i];
        out[2 * NTOT + NVEC] = (float)exp(-s);
    }
}

extern "C" void kernel_launch(void* const* d_in, const int* in_sizes, int n_in,
                              void* d_out, int out_size, void* d_ws, size_t ws_size,
                              hipStream_t stream) {
    const float* z  = (const float*)d_in[0];   // [64,64,32,32]
    const float* cb = (const float*)d_in[1];   // [1024,64]
    float* out = (float*)d_out;

    char* ws = (char*)d_ws;
    unsigned long long* keys = (unsigned long long*)(ws + 0);
    float* se   = (float*)(ws + 524288);
    int*   hist = (int*)(ws + 528384);

    init_kernel<<<256, 256, 0, stream>>>(keys, hist);
    se_kernel<<<4, 256, 0, stream>>>(cb, se);
    dim3 ag(NVEC / 128, 2);
    argmin_kernel<<<ag, 128, 0, stream>>>(z, cb, se, keys);
    scatter_kernel<<<NTOT / 1024, 256, 0, stream>>>(z, cb, keys, out);
    hist_kernel<<<NVEC / 256, 256, 0, stream>>>(keys, hist, out + 2 * NTOT);
    perp_kernel<<<1, 1024, 0, stream>>>(hist, out);
}

// Round 4
// 269.637 us; speedup vs baseline: 1.5264x; 1.2672x over previous
//
#include <hip/hip_runtime.h>
#include <math.h>

// Problem constants
#define NVEC   65536      // B*H*W = 64*32*32
#define CDIM   64
#define KBOOK  1024
#define NTOT   4194304    // B*C*H*W
#define KSPLIT 4
#define KCHUNK (KBOOK / KSPLIT)   // 256

// d_out layout (float32): [quantized_z: NTOT][quantized_z_st: NTOT][indices: NVEC][perplexity: 1]
// workspace: u64 keys[NVEC] @0 ; float se[KBOOK] @524288 ; int hist[KBOOK] @528384

// init keys, zero hist, and compute se (||e_k||^2, numpy pairwise 8-acc, rn intrinsics)
__global__ void prep_kernel(const float* __restrict__ cb, unsigned long long* __restrict__ keys,
                            float* __restrict__ se, int* __restrict__ hist) {
    int t = blockIdx.x * 256 + threadIdx.x;   // grid 256 -> t in [0, NVEC)
    keys[t] = 0xFFFFFFFFFFFFFFFFull;
    if (t < KBOOK) {
        hist[t] = 0;
        const float* row = cb + t * CDIM;
        float r[8];
#pragma unroll
        for (int j = 0; j < 8; ++j) r[j] = __fmul_rn(row[j], row[j]);
#pragma unroll
        for (int i = 8; i < 64; i += 8)
#pragma unroll
            for (int j = 0; j < 8; ++j) r[j] = __fadd_rn(r[j], __fmul_rn(row[i + j], row[i + j]));
        se[t] = __fadd_rn(__fadd_rn(__fadd_rn(r[0], r[1]), __fadd_rn(r[2], r[3])),
                          __fadd_rn(__fadd_rn(r[4], r[5]), __fadd_rn(r[6], r[7])));
    }
}

// Bit-exact dists = fl(fl(sx+se_k) - a_nk), a = ascending-c fmaf chain on zx=2z.
// zx[64] pinned into VGPRs via opaque asm (blocks invariant-load remat).
// K split 4 ways over blockIdx.y; halves merged via ordered-key atomicMin
// (value-then-index lexicographic == numpy first-min argmin).
__launch_bounds__(128, 4)
__global__ void argmin_kernel(const float* __restrict__ z, const float* __restrict__ cb,
                              const float* __restrict__ se,
                              unsigned long long* __restrict__ keys) {
    const int t = threadIdx.x;
    const int n = blockIdx.x * 128 + t;
    const int k0 = blockIdx.y * KCHUNK;
    const int b = n >> 10, hw = n & 1023;
    const float* zb = z + (size_t)b * (CDIM * 1024) + hw;

    // zx = 2*z (exact); sx = numpy pairwise 8-acc sum of fl(z^2)
    float zx[CDIM];
    float r[8];
#pragma unroll
    for (int c = 0; c < CDIM; ++c) {
        float zc = zb[c * 1024];
        zx[c] = zc + zc;
        float q = __fmul_rn(zc, zc);
        if (c < 8) r[c] = q;
        else r[c & 7] = __fadd_rn(r[c & 7], q);
    }
    const float sx = __fadd_rn(__fadd_rn(__fadd_rn(r[0], r[1]), __fadd_rn(r[2], r[3])),
                               __fadd_rn(__fadd_rn(r[4], r[5]), __fadd_rn(r[6], r[7])));

    // Pin zx in VGPRs: opaque def -> compiler cannot rematerialize the z loads
    // inside the k-loop (round-3 failure mode: VGPR_Count=56, reload per tile).
#pragma unroll
    for (int c = 0; c < CDIM; ++c) asm volatile("" : "+v"(zx[c]));

    float best = 3.4e38f;
    int bi = k0;

    for (int k = k0; k < k0 + KCHUNK; k += 4) {
        const float* __restrict__ row = cb + (size_t)k * CDIM;  // wave-uniform address
        float a0 = 0.f, a1 = 0.f, a2 = 0.f, a3 = 0.f;           // 4 indep fmaf chains
#pragma unroll
        for (int c = 0; c < CDIM; ++c) {
            a0 = fmaf(zx[c], row[c], a0);
            a1 = fmaf(zx[c], row[c + CDIM], a1);
            a2 = fmaf(zx[c], row[c + 2 * CDIM], a2);
            a3 = fmaf(zx[c], row[c + 3 * CDIM], a3);
        }
        const float d0 = __fsub_rn(__fadd_rn(sx, se[k]), a0);
        const float d1 = __fsub_rn(__fadd_rn(sx, se[k + 1]), a1);
        const float d2 = __fsub_rn(__fadd_rn(sx, se[k + 2]), a2);
        const float d3 = __fsub_rn(__fadd_rn(sx, se[k + 3]), a3);
        if (d0 < best) { best = d0; bi = k; }        // strict <, ascending k: first-min
        if (d1 < best) { best = d1; bi = k + 1; }
        if (d2 < best) { best = d2; bi = k + 2; }
        if (d3 < best) { best = d3; bi = k + 3; }
    }

    // ordered-float key: monotonic uint32 over all floats; idx in low bits
    unsigned int ob = __float_as_uint(best);
    ob = (ob & 0x80000000u) ? ~ob : (ob | 0x80000000u);
    atomicMin(&keys[n], ((unsigned long long)ob << 32) | (unsigned int)bi);
}

// quantized_z = cb[idx]; quantized_z_st = fl(z + fl(q - z)); float4-vectorized
__global__ void scatter_kernel(const float* __restrict__ z, const float* __restrict__ cb,
                               const unsigned long long* __restrict__ keys,
                               float* __restrict__ out) {
    const int o = (blockIdx.x * 256 + threadIdx.x) * 4;    // [0, NTOT), step 4
    const int b = o >> 16, c = (o >> 10) & 63, hw = o & 1023;
    const int n = (b << 10) | hw;
    float q[4];
#pragma unroll
    for (int j = 0; j < 4; ++j) {
        const int k = (int)(keys[n + j] & 0xFFFFFFFFu);
        q[j] = cb[k * CDIM + c];
    }
    const float4 zv = *(const float4*)(z + o);
    *(float4*)(out + o) = make_float4(q[0], q[1], q[2], q[3]);
    float4 st;
    st.x = __fadd_rn(zv.x, __fsub_rn(q[0], zv.x));
    st.y = __fadd_rn(zv.y, __fsub_rn(q[1], zv.y));
    st.z = __fadd_rn(zv.z, __fsub_rn(q[2], zv.z));
    st.w = __fadd_rn(zv.w, __fsub_rn(q[3], zv.w));
    *(float4*)(out + NTOT + o) = st;
}

// histogram + indices-as-float
__global__ void hist_kernel(const unsigned long long* __restrict__ keys, int* __restrict__ hist,
                            float* __restrict__ outIdxF) {
    __shared__ int lh[KBOOK];
    for (int i = threadIdx.x; i < KBOOK; i += 256) lh[i] = 0;
    __syncthreads();
    const int n = blockIdx.x * 256 + threadIdx.x;          // grid = 256 blocks
    const int k = (int)(keys[n] & 0xFFFFFFFFu);
    outIdxF[n] = (float)k;
    atomicAdd(&lh[k], 1);
    __syncthreads();
    for (int i = threadIdx.x; i < KBOOK; i += 256)
        if (lh[i]) atomicAdd(&hist[i], lh[i]);
}

__global__ void perp_kernel(const int* __restrict__ hist, float* __restrict__ out) {
    __shared__ double partial[16];
    const int t = threadIdx.x;  // 1024 threads
    const int c = hist[t];
    double term = 0.0;
    if (c > 0) { double p = (double)c / (double)NVEC; term = p * log(p); }
    for (int off = 32; off > 0; off >>= 1) term += __shfl_down(term, off);
    if ((t & 63) == 0) partial[t >> 6] = term;
    __syncthreads();
    if (t == 0) {
        double s = 0.0;
        for (int i = 0; i < 16; ++i) s += partial[i];
        out[2 * NTOT + NVEC] = (float)exp(-s);
    }
}

extern "C" void kernel_launch(void* const* d_in, const int* in_sizes, int n_in,
                              void* d_out, int out_size, void* d_ws, size_t ws_size,
                              hipStream_t stream) {
    const float* z  = (const float*)d_in[0];   // [64,64,32,32]
    const float* cb = (const float*)d_in[1];   // [1024,64]
    float* out = (float*)d_out;

    char* ws = (char*)d_ws;
    unsigned long long* keys = (unsigned long long*)(ws + 0);
    float* se   = (float*)(ws + 524288);
    int*   hist = (int*)(ws + 528384);

    prep_kernel<<<256, 256, 0, stream>>>(cb, keys, se, hist);
    dim3 ag(NVEC / 128, KSPLIT);
    argmin_kernel<<<ag, 128, 0, stream>>>(z, cb, se, keys);
    scatter_kernel<<<NTOT / 1024, 256, 0, stream>>>(z, cb, keys, out);
    hist_kernel<<<NVEC / 256, 256, 0, stream>>>(keys, hist, out + 2 * NTOT);
    perp_kernel<<<1, 1024, 0, stream>>>(hist, out);
}